// Round 11
// baseline (548.198 us; speedup 1.0000x reference)
//
#include <hip/hip_runtime.h>
#include <hip/hip_bf16.h>

namespace {
constexpr int S = 2048;
constexpr int D = 64;
constexpr float QSCALE = 0.18033688011112042f;  // (1/sqrt(64)) * log2(e)

using f32x4 = __attribute__((ext_vector_type(4))) float;
using bf16x8 = __attribute__((ext_vector_type(8))) short;

__device__ __forceinline__ short f2bf(float f) {
  return __builtin_bit_cast(short, __float2bfloat16(f));  // native RNE cvt
}
#if __has_builtin(__builtin_amdgcn_exp2f)
__device__ __forceinline__ float exp2_fast(float x) { return __builtin_amdgcn_exp2f(x); }
#else
__device__ __forceinline__ float exp2_fast(float x) { return exp2f(x); }
#endif

__device__ __forceinline__ void bar_lds() {  // lgkm-only barrier: vmem prefetch stays in flight
  asm volatile("s_waitcnt lgkmcnt(0)" ::: "memory");
  __builtin_amdgcn_s_barrier();
}
}  // namespace

// One block = (bh, q-tile pair (p, p+16)). Shared-k-range pairing:
//   zero-fill first (stores overlap compute everywhere),
//   A-shared kt=[0,p]: one staging -> QK/exp/PV for BOTH q-tiles,
//   A2 kt=[p+1,p+16]: qt1 only,
//   B  kt=[0,p+16]: one K staging -> normalized-a rows for BOTH q-tiles.
// 40KB LDS + VGPR<=128 -> 4 blocks/CU.
__global__ __launch_bounds__(256, 4) void attn_pair16(const float* __restrict__ qg,
                                                      const float* __restrict__ kg,
                                                      const float* __restrict__ vg,
                                                      float* __restrict__ outg) {
  __shared__ short kbuf[2][64 * 64];   // K[j][d] bf16, XOR-swizzled, dbuf
  __shared__ short vbuf[2][64 * 64];   // V^T[d][j] bf16, XOR-swizzled, dbuf
  __shared__ short pscr[4][16 * 64];   // per-wave p~ redistribution scratch

  const int tid = threadIdx.x;
  const int w = tid >> 6, lane = tid & 63, lg = lane >> 4, lr = lane & 15;

  // XCD-chunked map; stride-8 u -> next pair index (heavy/light alternating)
  const int u = blockIdx.x;                       // 1024 blocks
  const int logical = (u & 7) * 128 + (u >> 3);   // 1024 % 8 == 0
  const int bh = logical >> 4;
  const int ppi = logical & 15;
  const int p = (ppi & 1) ? (15 - (ppi >> 1)) : (ppi >> 1);
  const int NT0 = p + 1, NT1 = p + 17;            // qt0 = p, qt1 = p+16

  const size_t bh_off = (size_t)bh * S * D;
  float* const og = outg;
  float* const a_base = outg + (size_t)64 * S * D + (size_t)bh * S * S;
  const int asw = (lr & 7) << 3;

  const int igl0 = p * 64 + w * 16 + lr;          // lane's q-row in qt0
  const int igl1 = (p + 16) * 64 + w * 16 + lr;   // lane's q-row in qt1
  float* const arow0 = a_base + (size_t)igl0 * S;
  float* const arow1 = a_base + (size_t)igl1 * S;

  // ---- zero tiles FIRST: fire-and-forget NT stores drain under loop A ----
  {
    const f32x4 z = {0.f, 0.f, 0.f, 0.f};
    for (int zt = NT0; zt < S / 64; ++zt) {
#pragma unroll
      for (int jb = 0; jb < 4; ++jb)
        __builtin_nontemporal_store(z, (f32x4*)(arow0 + zt * 64 + jb * 16 + lg * 4));
    }
    for (int zt = NT1; zt < S / 64; ++zt) {
#pragma unroll
      for (int jb = 0; jb < 4; ++jb)
        __builtin_nontemporal_store(z, (f32x4*)(arow1 + zt * 64 + jb * 16 + lg * 4));
    }
  }

  // ---- Q B-fragments for both q-tiles (col i = lane's row, k = d), QSCALE folded ----
  bf16x8 qf0[2], qf1[2];
#pragma unroll
  for (int kh = 0; kh < 2; ++kh) {
    const float* qp0 = qg + bh_off + (size_t)igl0 * D + kh * 32 + lg * 8;
    const float* qp1 = qg + bh_off + (size_t)igl1 * D + kh * 32 + lg * 8;
    f32x4 a0 = *(const f32x4*)qp0, a1 = *(const f32x4*)(qp0 + 4);
    f32x4 b0 = *(const f32x4*)qp1, b1 = *(const f32x4*)(qp1 + 4);
    bf16x8 f0, f1;
#pragma unroll
    for (int e = 0; e < 4; ++e) {
      f0[e] = f2bf(a0[e] * QSCALE); f0[e + 4] = f2bf(a1[e] * QSCALE);
      f1[e] = f2bf(b0[e] * QSCALE); f1[e + 4] = f2bf(b1[e] * QSCALE);
    }
    qf0[kh] = f0; qf1[kh] = f1;
  }

  const int krow = tid >> 2, kc = (tid & 3) * 16;
  const int kswz = (krow & 7) << 3;
  const int vj = tid & 63, vd0 = (tid >> 6) * 16;

  f32x4 ka[4], va[4];

#define LOAD_K(kt_) do { const float* kp_ = kg + bh_off + (size_t)((kt_) * 64 + krow) * D + kc; \
    ka[0] = *(const f32x4*)(kp_);     ka[1] = *(const f32x4*)(kp_ + 4);                         \
    ka[2] = *(const f32x4*)(kp_ + 8); ka[3] = *(const f32x4*)(kp_ + 12); } while (0)
#define LOAD_V(kt_) do { const float* vp_ = vg + bh_off + (size_t)((kt_) * 64 + vj) * D + vd0;  \
    va[0] = *(const f32x4*)(vp_);     va[1] = *(const f32x4*)(vp_ + 4);                         \
    va[2] = *(const f32x4*)(vp_ + 8); va[3] = *(const f32x4*)(vp_ + 12); } while (0)
#define STAGE_K(buf_) do { bf16x8 kb_;                                                           \
    _Pragma("unroll") for (int e = 0; e < 4; ++e) { kb_[e] = f2bf(ka[0][e]); kb_[e+4] = f2bf(ka[1][e]); } \
    *(bf16x8*)(&kbuf[buf_][(krow * 64 + kc) ^ kswz]) = kb_;                                      \
    _Pragma("unroll") for (int e = 0; e < 4; ++e) { kb_[e] = f2bf(ka[2][e]); kb_[e+4] = f2bf(ka[3][e]); } \
    *(bf16x8*)(&kbuf[buf_][(krow * 64 + kc + 8) ^ kswz]) = kb_; } while (0)
#define STAGE_V(buf_) do {                                                                       \
    _Pragma("unroll") for (int i = 0; i < 4; ++i)                                                \
    _Pragma("unroll") for (int e = 0; e < 4; ++e) {                                              \
      const int d_ = vd0 + i * 4 + e;                                                            \
      vbuf[buf_][(d_ * 64 + vj) ^ ((d_ & 7) << 3)] = f2bf(va[i][e]); } } while (0)

  // QK section: sacc <- K(tile cur) x qf ; then exp/mask -> psc + l
#define QK_EXP(cur_, qf_, lacc_, maskrow_, domask_) do {                                         \
    f32x4 sacc_[4];                                                                              \
    _Pragma("unroll") for (int jb = 0; jb < 4; ++jb) sacc_[jb] = (f32x4){0.f,0.f,0.f,0.f};       \
    _Pragma("unroll") for (int kh = 0; kh < 2; ++kh) {                                           \
      _Pragma("unroll") for (int jb = 0; jb < 4; ++jb) {                                         \
        bf16x8 kf_ = *(const bf16x8*)(&kbuf[cur_][((jb*16+lr)*64 + kh*32 + lg*8) ^ asw]);        \
        sacc_[jb] = __builtin_amdgcn_mfma_f32_16x16x32_bf16(kf_, (qf_)[kh], sacc_[jb], 0,0,0);   \
      }                                                                                          \
    }                                                                                            \
    _Pragma("unroll") for (int jb = 0; jb < 4; ++jb) {                                           \
      short4 ps_;                                                                                \
      _Pragma("unroll") for (int r = 0; r < 4; ++r) {                                            \
        const int jgl_ = ktv * 64 + jb * 16 + lg * 4 + r;                                        \
        float pt_ = exp2_fast(sacc_[jb][r]);                                                     \
        if ((domask_) && jgl_ > (maskrow_)) pt_ = 0.f;                                           \
        (lacc_) += pt_;                                                                          \
        ((short*)&ps_)[r] = f2bf(pt_);                                                           \
      }                                                                                          \
      *(short4*)(&pscr[w][(lr * 64 + jb * 16 + lg * 4) ^ asw]) = ps_;                            \
    } } while (0)

#define PV(cur_, oacc_) do {                                                                     \
    _Pragma("unroll") for (int ks = 0; ks < 2; ++ks) {                                           \
      bf16x8 pa_ = *(const bf16x8*)(&pscr[w][(lr * 64 + ks * 32 + lg * 8) ^ asw]);               \
      _Pragma("unroll") for (int dg = 0; dg < 4; ++dg) {                                         \
        bf16x8 vb_ = *(const bf16x8*)(&vbuf[cur_][((dg*16+lr)*64 + ks*32 + lg*8) ^ asw]);        \
        (oacc_)[dg] = __builtin_amdgcn_mfma_f32_16x16x32_bf16(pa_, vb_, (oacc_)[dg], 0,0,0);     \
      }                                                                                          \
    } } while (0)

  float l0 = 0.f, l1 = 0.f;
  f32x4 oacc0[4], oacc1[4];
#pragma unroll
  for (int dg = 0; dg < 4; ++dg) {
    oacc0[dg] = (f32x4){0.f, 0.f, 0.f, 0.f};
    oacc1[dg] = (f32x4){0.f, 0.f, 0.f, 0.f};
  }

  // ================== A-shared: kt in [0, NT0): both q-tiles ==================
  LOAD_K(0); LOAD_V(0);
  STAGE_K(0); STAGE_V(0);
  bar_lds();
  for (int ktv = 0; ktv < NT0; ++ktv) {
    const int cur = ktv & 1;
    if (ktv + 1 < NT0) { LOAD_K(ktv + 1); LOAD_V(ktv + 1); }
    // qt0 (diag mask on its last tile)
    QK_EXP(cur, qf0, l0, igl0, (ktv == NT0 - 1));
    PV(cur, oacc0);
    // qt1 (k-range [0,p] is fully unmasked for rows >= (p+16)*64)
    QK_EXP(cur, qf1, l1, igl1, false);
    PV(cur, oacc1);
    if (ktv + 1 < NT0) { STAGE_K(cur ^ 1); STAGE_V(cur ^ 1); }
    bar_lds();
  }

  // rl0 + O0 write
  l0 += __shfl_xor(l0, 16, 64);
  l0 += __shfl_xor(l0, 32, 64);
  const float rlA0 = 1.f / l0;
  {
    float* const rlv = (float*)(&pscr[w][0]);
    if (lane < 16) rlv[lr] = rlA0;
    asm volatile("s_waitcnt lgkmcnt(0)" ::: "memory");
#pragma unroll
    for (int dg = 0; dg < 4; ++dg)
#pragma unroll
      for (int r = 0; r < 4; ++r)
        og[bh_off + (size_t)(p * 64 + w * 16 + lg * 4 + r) * D + dg * 16 + lr] =
            oacc0[dg][r] * rlv[lg * 4 + r];
  }

  // ================== A2: kt in [NT0, NT1): qt1 only ==================
  LOAD_K(NT0); LOAD_V(NT0);
  STAGE_K(0); STAGE_V(0);
  bar_lds();
  for (int kt2 = NT0; kt2 < NT1; ++kt2) {
    const int ktv = kt2;
    const int cur = (kt2 - NT0) & 1;
    if (kt2 + 1 < NT1) { LOAD_K(kt2 + 1); LOAD_V(kt2 + 1); }
    QK_EXP(cur, qf1, l1, igl1, (kt2 == NT1 - 1));
    PV(cur, oacc1);
    if (kt2 + 1 < NT1) { STAGE_K(cur ^ 1); STAGE_V(cur ^ 1); }
    bar_lds();
  }

  // rl1 + O1 write
  l1 += __shfl_xor(l1, 16, 64);
  l1 += __shfl_xor(l1, 32, 64);
  const float rlA1 = 1.f / l1;
  {
    float* const rlv = (float*)(&pscr[w][0]);
    if (lane < 16) rlv[lr] = rlA1;
    asm volatile("s_waitcnt lgkmcnt(0)" ::: "memory");
#pragma unroll
    for (int dg = 0; dg < 4; ++dg)
#pragma unroll
      for (int r = 0; r < 4; ++r)
        og[bh_off + (size_t)((p + 16) * 64 + w * 16 + lg * 4 + r) * D + dg * 16 + lr] =
            oacc1[dg][r] * rlv[lg * 4 + r];
  }

  // ========== B: kt in [0, NT1): one K staging emits BOTH rows' a ==========
  LOAD_K(0);
  STAGE_K(0);
  bar_lds();
  for (int ktv = 0; ktv < NT1; ++ktv) {
    const int cur = ktv & 1;
    if (ktv + 1 < NT1) LOAD_K(ktv + 1);

#pragma unroll
    for (int jb = 0; jb < 4; ++jb) {
      // shared kf reads serve both q-tiles' MFMAs
      bf16x8 kf0 = *(const bf16x8*)(&kbuf[cur][((jb * 16 + lr) * 64 + lg * 8) ^ asw]);
      bf16x8 kf1 = *(const bf16x8*)(&kbuf[cur][((jb * 16 + lr) * 64 + 32 + lg * 8) ^ asw]);
      if (ktv < NT0) {
        f32x4 s0 = {0.f, 0.f, 0.f, 0.f};
        s0 = __builtin_amdgcn_mfma_f32_16x16x32_bf16(kf0, qf0[0], s0, 0, 0, 0);
        s0 = __builtin_amdgcn_mfma_f32_16x16x32_bf16(kf1, qf0[1], s0, 0, 0, 0);
        f32x4 av;
        const bool diag0 = (ktv == NT0 - 1);
#pragma unroll
        for (int r = 0; r < 4; ++r) {
          const int jgl = ktv * 64 + jb * 16 + lg * 4 + r;
          float pt = exp2_fast(s0[r]);
          if (diag0 && jgl > igl0) pt = 0.f;
          av[r] = pt * rlA0;
        }
        __builtin_nontemporal_store(av, (f32x4*)(arow0 + ktv * 64 + jb * 16 + lg * 4));
      }
      {
        f32x4 s1 = {0.f, 0.f, 0.f, 0.f};
        s1 = __builtin_amdgcn_mfma_f32_16x16x32_bf16(kf0, qf1[0], s1, 0, 0, 0);
        s1 = __builtin_amdgcn_mfma_f32_16x16x32_bf16(kf1, qf1[1], s1, 0, 0, 0);
        f32x4 av;
        const bool diag1 = (ktv == NT1 - 1);
#pragma unroll
        for (int r = 0; r < 4; ++r) {
          const int jgl = ktv * 64 + jb * 16 + lg * 4 + r;
          float pt = exp2_fast(s1[r]);
          if (diag1 && jgl > igl1) pt = 0.f;
          av[r] = pt * rlA1;
        }
        __builtin_nontemporal_store(av, (f32x4*)(arow1 + ktv * 64 + jb * 16 + lg * 4));
      }
    }

    if (ktv + 1 < NT1) STAGE_K(cur ^ 1);
    bar_lds();
  }

#undef LOAD_K
#undef LOAD_V
#undef STAGE_K
#undef STAGE_V
#undef QK_EXP
#undef PV
}

extern "C" void kernel_launch(void* const* d_in, const int* in_sizes, int n_in,
                              void* d_out, int out_size, void* d_ws, size_t ws_size,
                              hipStream_t stream) {
  const float* q = (const float*)d_in[0];
  const float* k = (const float*)d_in[1];
  const float* v = (const float*)d_in[2];
  float* out = (float*)d_out;
  attn_pair16<<<dim3(1024), dim3(256), 0, stream>>>(q, k, v, out);
}

// Round 12
// 353.071 us; speedup vs baseline: 1.5527x; 1.5527x over previous
//
#include <hip/hip_runtime.h>
#include <hip/hip_bf16.h>

namespace {
constexpr int S = 2048;
constexpr int D = 64;
constexpr float QSCALE = 0.18033688011112042f;  // (1/sqrt(64)) * log2(e)

using f32x4 = __attribute__((ext_vector_type(4))) float;
using bf16x8 = __attribute__((ext_vector_type(8))) short;

__device__ __forceinline__ short f2bf(float f) {
  return __builtin_bit_cast(short, __float2bfloat16(f));  // native RNE cvt
}
#if __has_builtin(__builtin_amdgcn_exp2f)
__device__ __forceinline__ float exp2_fast(float x) { return __builtin_amdgcn_exp2f(x); }
#else
__device__ __forceinline__ float exp2_fast(float x) { return exp2f(x); }
#endif

__device__ __forceinline__ void bar_lds() {  // lgkm-only barrier: vmem prefetch stays in flight
  asm volatile("s_waitcnt lgkmcnt(0)" ::: "memory");
  __builtin_amdgcn_s_barrier();
}
}  // namespace

// One block = (bh, 64 q-rows). Zero-fill FIRST (stores overlap everyone's loop A),
// loop A: QK+exp-sum+PV (K/V dbuf);  loop B: QK recompute -> normalized a, with a
// 4-deep K buffer ring (vbuf is dead in B) -> 0.5 barriers/tile + 2-tile prefetch.
// 40KB LDS -> 4 blocks/CU.
__global__ __launch_bounds__(256, 4) void attn_fused(const float* __restrict__ qg,
                                                     const float* __restrict__ kg,
                                                     const float* __restrict__ vg,
                                                     float* __restrict__ outg) {
  __shared__ short stage4[4][64 * 64];  // A: [0..1]=K dbuf, [2..3]=V^T dbuf. B: 4-deep K ring.
  __shared__ short pscr[4][16 * 64];    // per-wave p~ redistribution scratch

  const int tid = threadIdx.x;
  const int w = tid >> 6, lane = tid & 63, lg = lane >> 4, lr = lane & 15;

  // XCD-chunked block map + long/short qt interleave for co-resident balance
  const int u = blockIdx.x;
  const int logical = (u & 7) * 256 + (u >> 3);  // 2048 % 8 == 0
  const int bh = logical >> 5;
  const int uu = logical & 31;
  const int qt = (uu & 1) ? (31 - (uu >> 1)) : (uu >> 1);
  const int qrow0 = qt * 64;
  const int NT = qt + 1;

  const size_t bh_off = (size_t)bh * S * D;
  float* const og = outg;
  float* const a_base = outg + (size_t)64 * S * D + (size_t)bh * S * S;
  const int asw = (lr & 7) << 3;

  const int igl = qrow0 + w * 16 + lr;  // this lane's q-row (QK col i / p row)

  const int krow = tid >> 2, kc = (tid & 3) * 16;
  const int kswz = (krow & 7) << 3;
  const int vj = tid & 63, vd0 = (tid >> 6) * 16;

  f32x4 ka[4], ka2[4], va[4];

#define LOAD_K_TO(dst_, kt_) do { const float* kp_ = kg + bh_off + (size_t)((kt_) * 64 + krow) * D + kc; \
    (dst_)[0] = *(const f32x4*)(kp_);     (dst_)[1] = *(const f32x4*)(kp_ + 4);                          \
    (dst_)[2] = *(const f32x4*)(kp_ + 8); (dst_)[3] = *(const f32x4*)(kp_ + 12); } while (0)
#define LOAD_V(kt_) do { const float* vp_ = vg + bh_off + (size_t)((kt_) * 64 + vj) * D + vd0;           \
    va[0] = *(const f32x4*)(vp_);     va[1] = *(const f32x4*)(vp_ + 4);                                  \
    va[2] = *(const f32x4*)(vp_ + 8); va[3] = *(const f32x4*)(vp_ + 12); } while (0)
#define STAGE_K_FROM(src_, buf_) do { bf16x8 kb_;                                                        \
    _Pragma("unroll") for (int e = 0; e < 4; ++e) { kb_[e] = f2bf((src_)[0][e]); kb_[e+4] = f2bf((src_)[1][e]); } \
    *(bf16x8*)(&stage4[buf_][(krow * 64 + kc) ^ kswz]) = kb_;                                            \
    _Pragma("unroll") for (int e = 0; e < 4; ++e) { kb_[e] = f2bf((src_)[2][e]); kb_[e+4] = f2bf((src_)[3][e]); } \
    *(bf16x8*)(&stage4[buf_][(krow * 64 + kc + 8) ^ kswz]) = kb_; } while (0)
#define STAGE_V(buf_) do {                                                                               \
    _Pragma("unroll") for (int i = 0; i < 4; ++i)                                                        \
    _Pragma("unroll") for (int e = 0; e < 4; ++e) {                                                      \
      const int d_ = vd0 + i * 4 + e;                                                                    \
      stage4[buf_][(d_ * 64 + vj) ^ ((d_ & 7) << 3)] = f2bf(va[i][e]); } } while (0)

  // ---- issue tile-0 K/V loads BEFORE the zero-fill store burst (latency hides) ----
  LOAD_K_TO(ka, 0);
  LOAD_V(0);

  // ---- zero tiles (j >= NT*64) FIRST: fire-and-forget NT stores ----
  {
    float* const arow = a_base + (size_t)igl * S;
    const f32x4 z = {0.f, 0.f, 0.f, 0.f};
    for (int zt = NT; zt < S / 64; ++zt) {
#pragma unroll
      for (int jb = 0; jb < 4; ++jb)
        __builtin_nontemporal_store(z, (f32x4*)(arow + zt * 64 + jb * 16 + lg * 4));
    }
  }

  // ---- Q B-fragment (col i = lane's row, k = d), QSCALE folded ----
  bf16x8 qf[2];
#pragma unroll
  for (int kh = 0; kh < 2; ++kh) {
    const float* qp = qg + bh_off + (size_t)igl * D + kh * 32 + lg * 8;
    f32x4 x0 = *(const f32x4*)(qp);
    f32x4 x1 = *(const f32x4*)(qp + 4);
    bf16x8 f;
#pragma unroll
    for (int e = 0; e < 4; ++e) {
      f[e] = f2bf(x0[e] * QSCALE);
      f[e + 4] = f2bf(x1[e] * QSCALE);
    }
    qf[kh] = f;
  }

  // =========================== loop A: l + O(unnormalized) ===========================
  STAGE_K_FROM(ka, 0);
  STAGE_V(2);
  bar_lds();

  float l_acc = 0.f;
  f32x4 oacc[4];
#pragma unroll
  for (int dg = 0; dg < 4; ++dg) oacc[dg] = (f32x4){0.f, 0.f, 0.f, 0.f};

  for (int kt = 0; kt < NT; ++kt) {
    const int cur = kt & 1;
    if (kt + 1 < NT) {  // prefetch next K/V tiles into regs
      LOAD_K_TO(ka, kt + 1);
      LOAD_V(kt + 1);
    }

    // QK^T: D[j][i], lane col i = lr, rows j = jb*16 + lg*4 + r
    f32x4 sacc[4];
#pragma unroll
    for (int jb = 0; jb < 4; ++jb) sacc[jb] = (f32x4){0.f, 0.f, 0.f, 0.f};
#pragma unroll
    for (int kh = 0; kh < 2; ++kh) {
#pragma unroll
      for (int jb = 0; jb < 4; ++jb) {
        bf16x8 kf = *(const bf16x8*)(&stage4[cur][((jb * 16 + lr) * 64 + kh * 32 + lg * 8) ^ asw]);
        sacc[jb] = __builtin_amdgcn_mfma_f32_16x16x32_bf16(kf, qf[kh], sacc[jb], 0, 0, 0);
      }
    }

    // p~ = exp2(s) (masked on diagonal tile); accumulate l; pscr for PV
    const bool diag = (kt == NT - 1);
#pragma unroll
    for (int jb = 0; jb < 4; ++jb) {
      short4 ps;
#pragma unroll
      for (int r = 0; r < 4; ++r) {
        const int jgl = kt * 64 + jb * 16 + lg * 4 + r;
        float pt = exp2_fast(sacc[jb][r]);
        if (diag && jgl > igl) pt = 0.f;
        l_acc += pt;
        ((short*)&ps)[r] = f2bf(pt);
      }
      *(short4*)(&pscr[w][(lr * 64 + jb * 16 + lg * 4) ^ asw]) = ps;
    }

    // PV: O[i][d] += p~ V (pscr same-wave)
#pragma unroll
    for (int ks = 0; ks < 2; ++ks) {
      bf16x8 pa = *(const bf16x8*)(&pscr[w][(lr * 64 + ks * 32 + lg * 8) ^ asw]);
#pragma unroll
      for (int dg = 0; dg < 4; ++dg) {
        bf16x8 vb = *(const bf16x8*)(&stage4[2 + cur][((dg * 16 + lr) * 64 + ks * 32 + lg * 8) ^ asw]);
        oacc[dg] = __builtin_amdgcn_mfma_f32_16x16x32_bf16(pa, vb, oacc[dg], 0, 0, 0);
      }
    }

    if (kt + 1 < NT) {  // stage next tile into the other buffers
      STAGE_K_FROM(ka, cur ^ 1);
      STAGE_V(2 + (cur ^ 1));
    }
    bar_lds();
  }

  // ---- rl: reduce partials across lg; lane then holds rl for its row igl ----
  l_acc += __shfl_xor(l_acc, 16, 64);
  l_acc += __shfl_xor(l_acc, 32, 64);
  const float rlA = 1.f / l_acc;

  // O rescale needs rl at rows w*16+lg*4+r: bounce via per-wave pscr region
  {
    float* const rlv = (float*)(&pscr[w][0]);
    if (lane < 16) rlv[lr] = rlA;
    asm volatile("s_waitcnt lgkmcnt(0)" ::: "memory");  // same-wave write->read
#pragma unroll
    for (int dg = 0; dg < 4; ++dg) {
#pragma unroll
      for (int r = 0; r < 4; ++r) {
        const int il = qrow0 + w * 16 + lg * 4 + r;
        og[bh_off + (size_t)il * D + dg * 16 + lr] = oacc[dg][r] * rlv[lg * 4 + r];
      }
    }
  }

  // ======== loop B: normalized-a stream, 4-deep K ring, 1 barrier / 2 tiles ========
  float* const arow = a_base + (size_t)igl * S;

#define B_TILE(kt_, buf_) do {                                                                   \
    f32x4 sacc_[4];                                                                              \
    _Pragma("unroll") for (int jb = 0; jb < 4; ++jb) sacc_[jb] = (f32x4){0.f,0.f,0.f,0.f};       \
    _Pragma("unroll") for (int kh = 0; kh < 2; ++kh) {                                           \
      _Pragma("unroll") for (int jb = 0; jb < 4; ++jb) {                                         \
        bf16x8 kf_ = *(const bf16x8*)(&stage4[buf_][((jb*16+lr)*64 + kh*32 + lg*8) ^ asw]);      \
        sacc_[jb] = __builtin_amdgcn_mfma_f32_16x16x32_bf16(kf_, qf[kh], sacc_[jb], 0, 0, 0);    \
      }                                                                                          \
    }                                                                                            \
    const bool diag_ = ((kt_) == NT - 1);                                                        \
    _Pragma("unroll") for (int jb = 0; jb < 4; ++jb) {                                           \
      f32x4 av_;                                                                                 \
      _Pragma("unroll") for (int r = 0; r < 4; ++r) {                                            \
        const int jgl_ = (kt_) * 64 + jb * 16 + lg * 4 + r;                                      \
        float pt_ = exp2_fast(sacc_[jb][r]);                                                     \
        if (diag_ && jgl_ > igl) pt_ = 0.f;                                                      \
        av_[r] = pt_ * rlA;                                                                      \
      }                                                                                          \
      __builtin_nontemporal_store(av_, (f32x4*)(arow + (kt_) * 64 + jb * 16 + lg * 4));          \
    } } while (0)

  // prologue: stage tiles 0 (and 1) into ring slots 0,1
  LOAD_K_TO(ka, 0);
  if (NT > 1) LOAD_K_TO(ka2, 1);
  STAGE_K_FROM(ka, 0);
  if (NT > 1) STAGE_K_FROM(ka2, 1);
  bar_lds();

  for (int t0 = 0; t0 < NT; t0 += 2) {
    // prefetch the NEXT pair into regs (2 tiles deep)
    if (t0 + 2 < NT) LOAD_K_TO(ka, t0 + 2);
    if (t0 + 3 < NT) LOAD_K_TO(ka2, t0 + 3);

    B_TILE(t0, (t0 & 3));
    if (t0 + 1 < NT) B_TILE(t0 + 1, ((t0 + 1) & 3));

    // stage next pair into the OTHER ring half while this pair was being read
    if (t0 + 2 < NT) STAGE_K_FROM(ka, ((t0 + 2) & 3));
    if (t0 + 3 < NT) STAGE_K_FROM(ka2, ((t0 + 3) & 3));
    bar_lds();  // one barrier per pair
  }

#undef B_TILE
#undef LOAD_K_TO
#undef LOAD_V
#undef STAGE_K_FROM
#undef STAGE_V
}

extern "C" void kernel_launch(void* const* d_in, const int* in_sizes, int n_in,
                              void* d_out, int out_size, void* d_ws, size_t ws_size,
                              hipStream_t stream) {
  const float* q = (const float*)d_in[0];
  const float* k = (const float*)d_in[1];
  const float* v = (const float*)d_in[2];
  float* out = (float*)d_out;
  attn_fused<<<dim3(2048), dim3(256), 0, stream>>>(q, k, v, out);
}